// Round 2
// baseline (1416.748 us; speedup 1.0000x reference)
//
#include <hip/hip_runtime.h>
#include <hip/hip_bf16.h>

// QLSTM: T=512, B=256, D=128, H=256.  z = [x,h] @ W^T + b, W=[4H,384]
// Round 10: width-4 chains, W fully register-resident.
//  - Grid 64 blocks x 1024 threads (16 waves). Block (bg = blockIdx&15,
//    jg = blockIdx>>4): 16 batch rows x 64 H-cols (N=256 gate-outputs).
//    Chain = 4 blocks sharing bg, stride 16 -> same XCD under round-robin.
//  - W slice [256 x 384] lives in VGPRs: wave w owns output rows
//    g=w>>2, jc=(w&3)*16+l16; 12 short8 B-frags = 48 VGPR. No W_s, no
//    W ds_reads -> MFMA B-operand straight from registers.
//  - Exchange: thread polls ONE dwordx4 (4 tagged h-words) -> 16B/round
//    (r8 polled 64B). Fast sc0 plane, NO sleep (r9's sleep regressed);
//    bounded tries then sc1 fallback that always succeeds (proven).
//  - comb_s row = [xA 0..127 | h 128..383 | xB 384..511]: x double-buffered
//    by step parity so end-of-iter x-part MFMA needs no extra barrier.
//    2 barriers/step total.

#define T_STEPS 512
#define BATCH   256
#define DIN     128
#define HID     256
#define KDIM    384
#define LDK2    520   // comb row stride in shorts (1040 B, 16B-aligned)
#define GRIDN   64
#define BLOCKT  1024
#define NPOLL   96    // bounded fast-poll tries before sc1 fallback

typedef __attribute__((ext_vector_type(8))) short short8;
typedef __attribute__((ext_vector_type(4))) short short4v;
typedef __attribute__((ext_vector_type(4))) float f32x4;

__device__ __forceinline__ unsigned short f2bf(float f) {
    unsigned u = __float_as_uint(f);
    unsigned r = (u + 0x7FFFu + ((u >> 16) & 1u)) >> 16;
    return (unsigned short)r;
}
__device__ __forceinline__ float bf2f(unsigned short s) {
    return __uint_as_float(((unsigned)s) << 16);
}
__device__ __forceinline__ float sigmoid_f(float x) {
    return 1.f / (1.f + __expf(-x));
}
__device__ __forceinline__ float tanh_f(float x) {
    float e = __expf(2.f * x);
    return 1.f - 2.f / (e + 1.f);
}
// ---- fused poll load: 1 x dwordx4 + waitcnt in ONE asm block ----
__device__ __forceinline__ void poll_load1_sc0(const unsigned int* p, uint4& a) {
    asm volatile(
        "global_load_dwordx4 %0, %1, off sc0\n\t"
        "s_waitcnt vmcnt(0)"
        : "=&v"(a) : "v"(p) : "memory");
}
__device__ __forceinline__ void poll_load1_sc1(const unsigned int* p, uint4& a) {
    asm volatile(
        "global_load_dwordx4 %0, %1, off sc1\n\t"
        "s_waitcnt vmcnt(0)"
        : "=&v"(a) : "v"(p) : "memory");
}
__device__ __forceinline__ void store_plain_u32(unsigned int* p, unsigned int v) {
    asm volatile("global_store_dword %0, %1, off" :: "v"(p), "v"(v) : "memory");
}
__device__ __forceinline__ void store_sc1_u32(unsigned int* p, unsigned int v) {
    asm volatile("global_store_dword %0, %1, off sc1" :: "v"(p), "v"(v) : "memory");
}
__device__ __forceinline__ unsigned pack2bf(unsigned lo, unsigned hi) {
    return (hi & 0xFFFF0000u) | (lo >> 16);
}
__device__ __forceinline__ bool tags_ok1(const uint4& a, unsigned tag) {
    return ((a.x ^ tag) & 0xFFFFu) == 0 && ((a.y ^ tag) & 0xFFFFu) == 0 &&
           ((a.z ^ tag) & 0xFFFFu) == 0 && ((a.w ^ tag) & 0xFFFFu) == 0;
}

// ---- pack weights: Wpack[n][k] bf16, n = g*256 + j, row-major [1024][384] ----
__global__ __launch_bounds__(256) void pack_w(
    const float* __restrict__ Wf, const float* __restrict__ Wi,
    const float* __restrict__ Wg, const float* __restrict__ Wo,
    unsigned short* __restrict__ Wp) {
    int idx = blockIdx.x * 256 + threadIdx.x;
    int n = idx / KDIM;
    int k = idx - n * KDIM;
    int g = n >> 8, j = n & 255;
    const float* s = (g == 0) ? Wf : (g == 1) ? Wi : (g == 2) ? Wg : Wo;
    Wp[idx] = f2bf(s[j * KDIM + k]);
}

__global__ __launch_bounds__(256) void pack_b(
    const float* __restrict__ bf, const float* __restrict__ bi,
    const float* __restrict__ bg, const float* __restrict__ bo,
    float* __restrict__ bp) {
    int n = blockIdx.x * 256 + threadIdx.x;
    int g = n >> 8, j = n & 255;
    const float* s = (g == 0) ? bf : (g == 1) ? bi : (g == 2) ? bg : bo;
    bp[n] = s[j];
}

// ---- zero all 4 exchange planes: fast[2] + slow[2] (h_0 = 0, tag 0) ----
__global__ __launch_bounds__(256) void init_k(unsigned int* __restrict__ hxp) {
    int tid = blockIdx.x * 256 + threadIdx.x;   // grid 256 -> 65536
    hxp[tid] = 0u;
    hxp[65536 + tid] = 0u;
    hxp[131072 + tid] = 0u;
    hxp[196608 + tid] = 0u;
}

// ---- persistent LSTM: all 512 steps in one launch ----
__global__ __launch_bounds__(BLOCKT, 1) void lstm_persist(
    const float* __restrict__ X,            // [T,B,D] fp32
    const unsigned short* __restrict__ W,   // [1024][384] bf16
    const float* __restrict__ bias,         // [1024]
    unsigned int* __restrict__ hxp,         // fast[2][B][H] + slow[2][B][H]
    unsigned short* __restrict__ hist,      // [T][B][H] bf16
    float* __restrict__ out) {
    __shared__ __align__(16) unsigned short comb_s[16 * LDK2]; // 16640 B
    __shared__ __align__(16) float z_s[16 * 272];              // 17408 B
    __shared__ int fastok_s;

    const int tid = threadIdx.x;            // 0..1023
    const int bg = blockIdx.x & 15, jg = blockIdx.x >> 4;   // jg 0..3
    const int b0 = bg * 16, j0 = jg * 64;
    const int wave = tid >> 6, lane = tid & 63;             // wave 0..15
    const int l16 = lane & 15, quad = lane >> 4;
    const int bi = wave, jj = tid & 63;     // thread owns (b0+bi, j0+jj)
    const int b = b0 + bi, j = j0 + jj;

    // ---- W slice into registers: wave w -> gate g=w>>2, cols (w&3)*16+l16 ----
    const int gw = wave >> 2, jcw = ((wave & 3) << 4) + l16;
    const unsigned short* wrow =
        W + (size_t)(gw * HID + j0 + jcw) * KDIM + quad * 8;
    short8 wb[12];
#pragma unroll
    for (int kt = 0; kt < 12; ++kt) wb[kt] = *(const short8*)(wrow + kt * 32);

    const float bs0 = bias[0 * HID + j];
    const float bs1 = bias[1 * HID + j];
    const float bs2 = bias[2 * HID + j];
    const float bs3 = bias[3 * HID + j];
    if (tid == 0) fastok_s = 1;

    float c_reg = 0.f;
    float h_final = 0.f;

    // A-frag pointer (proven layout): row = batch l16, 8 shorts at quad*8
    const unsigned short* arow = &comb_s[l16 * LDK2 + quad * 8];
    unsigned short* xrow = &comb_s[bi * LDK2];   // staging row for this thread

    // ---- prologue: stage x_0 into xA, prefetch x_1, x-part MFMA for x_0 ----
    float2 xv = *(const float2*)(X + (size_t)b * DIN + jj * 2);
    {
        unsigned lo = f2bf(xv.x), hi = f2bf(xv.y);
        *(unsigned*)(&xrow[jj * 2]) = (hi << 16) | lo;
    }
    xv = *(const float2*)(X + (size_t)BATCH * DIN + (size_t)b * DIN + jj * 2);
    __syncthreads();

    f32x4 acc_x0 = {0.f, 0.f, 0.f, 0.f}, acc_x1 = {0.f, 0.f, 0.f, 0.f};
#pragma unroll
    for (int kp = 0; kp < 2; ++kp) {
        short8 a0 = *(const short8*)(arow + (2 * kp) * 32);
        short8 a1 = *(const short8*)(arow + (2 * kp + 1) * 32);
        acc_x0 = __builtin_amdgcn_mfma_f32_16x16x32_bf16(a0, wb[2 * kp], acc_x0, 0, 0, 0);
        acc_x1 = __builtin_amdgcn_mfma_f32_16x16x32_bf16(a1, wb[2 * kp + 1], acc_x1, 0, 0, 0);
    }

    for (int k = 0; k < T_STEPS; ++k) {
        const unsigned tag = (unsigned)k;
        // thread polls 4 h-words: row b, cols jj*4..jj*4+3 (one dwordx4)
        const unsigned int* fb =
            hxp + (k & 1) * 65536 + (size_t)b * HID + jj * 4;
        const unsigned int* sb = fb + 131072;    // slow plane
        uint4 aq;
        const int usefast = fastok_s;            // racy read is fine (hint only)

        // ---- poll h_k: fast (bounded, tight) then slow (guaranteed) ----
        if (usefast) {
            int tries = NPOLL;
            bool ok = false;
            for (;;) {
                poll_load1_sc0(fb, aq);
                if (tags_ok1(aq, tag)) { ok = true; break; }
                if (--tries == 0) break;
            }
            if (!ok) {                       // bounded fallback: ALWAYS succeeds
                fastok_s = 0;
                for (;;) {
                    poll_load1_sc1(sb, aq);
                    if (tags_ok1(aq, tag)) break;
                    __builtin_amdgcn_s_sleep(1);
                }
            }
        } else {
            for (;;) {
                poll_load1_sc1(sb, aq);
                if (tags_ok1(aq, tag)) break;
                __builtin_amdgcn_s_sleep(1);
            }
        }

        // extract 4 bf16 -> comb_s[bi][128 + jj*4] (h region)
        {
            uint2 pp;
            pp.x = pack2bf(aq.x, aq.y);
            pp.y = pack2bf(aq.z, aq.w);
            *(uint2*)(&xrow[128 + jj * 4]) = pp;
        }
        // stage x_{k+1} into parity region; prefetch x_{k+2}
        if (k + 1 < T_STEPS) {
            unsigned lo = f2bf(xv.x), hi = f2bf(xv.y);
            const int xoff = ((k + 1) & 1) ? 384 : 0;
            *(unsigned*)(&xrow[xoff + jj * 2]) = (hi << 16) | lo;
            if (k + 2 < T_STEPS)
                xv = *(const float2*)(X + (size_t)(k + 2) * BATCH * DIN +
                                      (size_t)b * DIN + jj * 2);
        }
        __syncthreads();   // barrier 1: h + x staged

        // ---- h-part MFMA (K=128..383), seeded with precomputed x-part ----
        f32x4 acc0 = acc_x0, acc1 = acc_x1;
#pragma unroll
        for (int kp = 0; kp < 4; ++kp) {
            short8 a0 = *(const short8*)(arow + (4 + 2 * kp) * 32);
            short8 a1 = *(const short8*)(arow + (5 + 2 * kp) * 32);
            acc0 = __builtin_amdgcn_mfma_f32_16x16x32_bf16(a0, wb[4 + 2 * kp], acc0, 0, 0, 0);
            acc1 = __builtin_amdgcn_mfma_f32_16x16x32_bf16(a1, wb[5 + 2 * kp], acc1, 0, 0, 0);
        }
#pragma unroll
        for (int r = 0; r < 4; ++r)
            z_s[wave * 272 + (quad * 4 + r) * 17 + l16] = acc0[r] + acc1[r];
        __syncthreads();   // barrier 2: z staged

        // ---- gates; dual-store h FIRST (chain-critical) ----
        // z for (g, col jj): wave = g*4 + (jj>>4), col = jj&15, row = bi
        const int zc = bi * 17 + (jj & 15);
        const int zw = (jj >> 4) * 272;
        float zf = z_s[zw + 0 * 1088 + zc] + bs0;
        float zi = z_s[zw + 1 * 1088 + zc] + bs1;
        float zg = z_s[zw + 2 * 1088 + zc] + bs2;
        float zo = z_s[zw + 3 * 1088 + zc] + bs3;
        float fg = sigmoid_f(zf);
        float ig = sigmoid_f(zi);
        float gg = tanh_f(zg);
        float og = sigmoid_f(zo);
        c_reg = fg * c_reg + ig * gg;
        float hval = og * tanh_f(c_reg);
        unsigned short hb = f2bf(hval);
        unsigned int hword = ((unsigned)hb << 16) | (unsigned)(k + 1);
        unsigned int* fdst = hxp + ((k + 1) & 1) * 65536 + (size_t)b * HID + j;
        store_plain_u32(fdst, hword);             // fast plane (producer's L2)
        store_sc1_u32(fdst + 131072, hword);      // slow plane (proven path)
        hist[(size_t)k * BATCH * HID + (size_t)b * HID + j] = hb;

        // ---- x-part MFMA for x_{k+1} (register W, parity LDS region) ----
        if (k + 1 < T_STEPS) {
            const int xoff = ((k + 1) & 1) ? 384 : 0;
            f32x4 ax0 = {0.f, 0.f, 0.f, 0.f}, ax1 = {0.f, 0.f, 0.f, 0.f};
#pragma unroll
            for (int kp = 0; kp < 2; ++kp) {
                short8 a0 = *(const short8*)(arow + xoff + (2 * kp) * 32);
                short8 a1 = *(const short8*)(arow + xoff + (2 * kp + 1) * 32);
                ax0 = __builtin_amdgcn_mfma_f32_16x16x32_bf16(a0, wb[2 * kp], ax0, 0, 0, 0);
                ax1 = __builtin_amdgcn_mfma_f32_16x16x32_bf16(a1, wb[2 * kp + 1], ax1, 0, 0, 0);
            }
            acc_x0 = ax0; acc_x1 = ax1;
        } else {
            h_final = hval;
        }
    }

    // epilogue: hx (fp32) and cx outputs
    out[T_STEPS * BATCH * 2 + (size_t)b * HID + j] = h_final;
    out[T_STEPS * BATCH * 2 + BATCH * HID + (size_t)b * HID + j] = c_reg;
}

// ---- classifier head: one wave per (t,b) row ----
__global__ __launch_bounds__(256) void probs_k(
    const unsigned short* __restrict__ hist, const float* __restrict__ Wc,
    const float* __restrict__ bc, float* __restrict__ out) {
    const int wave = threadIdx.x >> 6, lane = threadIdx.x & 63;
    const size_t row = (size_t)blockIdx.x * 4 + wave;   // row = t*256+b < 131072
    const unsigned short* h = hist + row * HID;
    short4v hv = *(const short4v*)(h + lane * 4);
    const float4 wv = *(const float4*)(Wc + lane * 4);
    float p = bf2f((unsigned short)hv.x) * wv.x + bf2f((unsigned short)hv.y) * wv.y +
              bf2f((unsigned short)hv.z) * wv.z + bf2f((unsigned short)hv.w) * wv.w;
#pragma unroll
    for (int off = 32; off >= 1; off >>= 1) p += __shfl_down(p, off);
    if (lane == 0) {
        float prob = 1.f / (1.f + __expf(-(p + bc[0])));
        out[row * 2]     = prob;
        out[row * 2 + 1] = 1.f - prob;
    }
}

extern "C" void kernel_launch(void* const* d_in, const int* in_sizes, int n_in,
                              void* d_out, int out_size, void* d_ws, size_t ws_size,
                              hipStream_t stream) {
    const float* X  = (const float*)d_in[0];
    const float* Wf = (const float*)d_in[1];
    const float* bfp= (const float*)d_in[2];
    const float* Wi = (const float*)d_in[3];
    const float* bip= (const float*)d_in[4];
    const float* Wg = (const float*)d_in[5];
    const float* bgp= (const float*)d_in[6];
    const float* Wo = (const float*)d_in[7];
    const float* bop= (const float*)d_in[8];
    const float* Wc = (const float*)d_in[9];
    const float* bc = (const float*)d_in[10];
    float* out = (float*)d_out;

    char* ws = (char*)d_ws;
    unsigned short* Wpack = (unsigned short*)(ws);               // 786432 B
    float* bias = (float*)(ws + 786432);                         // 4096 B
    unsigned int* hxp = (unsigned int*)(ws + 790528);            // 1048576 B
    unsigned short* hist = (unsigned short*)(ws + 1839104);      // 67108864 B

    pack_w<<<1536, 256, 0, stream>>>(Wf, Wi, Wg, Wo, Wpack);
    pack_b<<<4, 256, 0, stream>>>(bfp, bip, bgp, bop, bias);
    init_k<<<256, 256, 0, stream>>>(hxp);

    void* kargs[6] = {(void*)&X, (void*)&Wpack, (void*)&bias,
                      (void*)&hxp, (void*)&hist, (void*)&out};
    (void)hipLaunchCooperativeKernel((const void*)lstm_persist, dim3(GRIDN),
                                     dim3(BLOCKT), kargs, 0, stream);

    probs_k<<<32768, 256, 0, stream>>>(hist, Wc, bc, out);
}

// Round 3
// 1203.205 us; speedup vs baseline: 1.1775x; 1.1775x over previous
//
#include <hip/hip_runtime.h>
#include <hip/hip_bf16.h>
#include <hip/hip_cooperative_groups.h>

namespace cg = cooperative_groups;

// QLSTM: T=512, B=256, D=128, H=256.  z = [x,h] @ W^T + b, W=[4H,384]
// Round 11: r8 kernel (proven best, 1070us) with ONE change: XCD-VERIFIED
// chain placement. r9/r10 (narrower chains) both regressed -> exchange
// latency, not poll bandwidth, dominates. Hypothesis: the "round-robin =>
// stride-16 blocks share an XCD" assumption is false under cooperative
// dispatch, so every fast sc0 poll hits a stale line in the consumer's own
// (different-XCD) L2, trips the NPOLL fallback, and the WHOLE run uses the
// slow sc1/L3 plane (~2us/step). Fix: each block reads its physical XCD via
// s_getreg(HW_REG_XCC_ID) and claims a role (bg,jg) from that XCD's pool so
// each 16-member bg-chain is same-XCD BY CONSTRUCTION. Mis-claims (if any)
// only degrade to the existing adaptive sc1 fallback -> correctness and
// liveness unchanged.

#define T_STEPS 512
#define BATCH   256
#define DIN     128
#define HID     256
#define KDIM    384
#define LDK     392   // padded LDS row stride (shorts)
#define GRIDN   256
#define NPOLL   96    // bounded fast-poll tries before sc1 fallback

typedef __attribute__((ext_vector_type(8))) short short8;
typedef __attribute__((ext_vector_type(4))) short short4v;
typedef __attribute__((ext_vector_type(4))) float f32x4;

// ---- bootstrap state (device globals; re-zeroed by init_k every launch) ----
__device__ unsigned boot_percxd[8];
__device__ unsigned boot_claimed[8];   // 256-bit role bitmask

__device__ __forceinline__ unsigned short f2bf(float f) {
    unsigned u = __float_as_uint(f);
    unsigned r = (u + 0x7FFFu + ((u >> 16) & 1u)) >> 16;
    return (unsigned short)r;
}
__device__ __forceinline__ float bf2f(unsigned short s) {
    return __uint_as_float(((unsigned)s) << 16);
}
__device__ __forceinline__ float sigmoid_f(float x) {
    return 1.f / (1.f + __expf(-x));
}
__device__ __forceinline__ float tanh_f(float x) {
    float e = __expf(2.f * x);
    return 1.f - 2.f / (e + 1.f);
}
// ---- fused poll loads: 4 x dwordx4 + waitcnt in ONE asm block (r4 idiom) ----
__device__ __forceinline__ void poll_load_sc0(const unsigned int* p, uint4& a,
                                              uint4& b, uint4& c, uint4& d) {
    asm volatile(
        "global_load_dwordx4 %0, %4, off sc0\n\t"
        "global_load_dwordx4 %1, %4, off offset:16 sc0\n\t"
        "global_load_dwordx4 %2, %4, off offset:32 sc0\n\t"
        "global_load_dwordx4 %3, %4, off offset:48 sc0\n\t"
        "s_waitcnt vmcnt(0)"
        : "=&v"(a), "=&v"(b), "=&v"(c), "=&v"(d) : "v"(p) : "memory");
}
__device__ __forceinline__ void poll_load_sc1(const unsigned int* p, uint4& a,
                                              uint4& b, uint4& c, uint4& d) {
    asm volatile(
        "global_load_dwordx4 %0, %4, off sc1\n\t"
        "global_load_dwordx4 %1, %4, off offset:16 sc1\n\t"
        "global_load_dwordx4 %2, %4, off offset:32 sc1\n\t"
        "global_load_dwordx4 %3, %4, off offset:48 sc1\n\t"
        "s_waitcnt vmcnt(0)"
        : "=&v"(a), "=&v"(b), "=&v"(c), "=&v"(d) : "v"(p) : "memory");
}
__device__ __forceinline__ void store_plain_u32(unsigned int* p, unsigned int v) {
    asm volatile("global_store_dword %0, %1, off" :: "v"(p), "v"(v) : "memory");
}
__device__ __forceinline__ void store_sc1_u32(unsigned int* p, unsigned int v) {
    asm volatile("global_store_dword %0, %1, off sc1" :: "v"(p), "v"(v) : "memory");
}
__device__ __forceinline__ unsigned pack2bf(unsigned lo, unsigned hi) {
    return (hi & 0xFFFF0000u) | (lo >> 16);
}
__device__ __forceinline__ bool tags_ok(const uint4& a, const uint4& b,
                                        const uint4& c, const uint4& d,
                                        unsigned tag) {
    return ((a.x ^ tag) & 0xFFFFu) == 0 && ((a.y ^ tag) & 0xFFFFu) == 0 &&
           ((a.z ^ tag) & 0xFFFFu) == 0 && ((a.w ^ tag) & 0xFFFFu) == 0 &&
           ((b.x ^ tag) & 0xFFFFu) == 0 && ((b.y ^ tag) & 0xFFFFu) == 0 &&
           ((b.z ^ tag) & 0xFFFFu) == 0 && ((b.w ^ tag) & 0xFFFFu) == 0 &&
           ((c.x ^ tag) & 0xFFFFu) == 0 && ((c.y ^ tag) & 0xFFFFu) == 0 &&
           ((c.z ^ tag) & 0xFFFFu) == 0 && ((c.w ^ tag) & 0xFFFFu) == 0 &&
           ((d.x ^ tag) & 0xFFFFu) == 0 && ((d.y ^ tag) & 0xFFFFu) == 0 &&
           ((d.z ^ tag) & 0xFFFFu) == 0 && ((d.w ^ tag) & 0xFFFFu) == 0;
}

// ---- pack weights: Wpack[n][k] bf16, n = g*256 + j, row-major [1024][384] ----
__global__ __launch_bounds__(256) void pack_w(
    const float* __restrict__ Wf, const float* __restrict__ Wi,
    const float* __restrict__ Wg, const float* __restrict__ Wo,
    unsigned short* __restrict__ Wp) {
    int idx = blockIdx.x * 256 + threadIdx.x;
    int n = idx / KDIM;
    int k = idx - n * KDIM;
    int g = n >> 8, j = n & 255;
    const float* s = (g == 0) ? Wf : (g == 1) ? Wi : (g == 2) ? Wg : Wo;
    Wp[idx] = f2bf(s[j * KDIM + k]);
}

__global__ __launch_bounds__(256) void pack_b(
    const float* __restrict__ bf, const float* __restrict__ bi,
    const float* __restrict__ bg, const float* __restrict__ bo,
    float* __restrict__ bp) {
    int n = blockIdx.x * 256 + threadIdx.x;
    int g = n >> 8, j = n & 255;
    const float* s = (g == 0) ? bf : (g == 1) ? bi : (g == 2) ? bg : bo;
    bp[n] = s[j];
}

// ---- zero exchange planes + bootstrap state (h_0 = 0, tag 0) ----
__global__ __launch_bounds__(256) void init_k(unsigned int* __restrict__ hxp) {
    int tid = blockIdx.x * 256 + threadIdx.x;   // grid 256 -> 65536
    hxp[tid] = 0u;
    hxp[65536 + tid] = 0u;
    hxp[131072 + tid] = 0u;
    hxp[196608 + tid] = 0u;
    if (tid < 8) {
        boot_percxd[tid] = 0u;
        boot_claimed[tid] = 0u;
    }
}

// ---- persistent LSTM: all 512 steps in one launch ----
__global__ __launch_bounds__(256, 1) void lstm_persist(
    const float* __restrict__ X,            // [T,B,D] fp32
    const unsigned short* __restrict__ W,   // [1024][384] bf16
    const float* __restrict__ bias,         // [1024]
    unsigned int* __restrict__ hxp,         // fast[2][B][H] + slow[2][B][H]
    unsigned short* __restrict__ hist,      // [T][B][H] bf16
    float* __restrict__ out) {
    __shared__ __align__(16) unsigned short W_s[64 * LDK];    // 50176 B
    __shared__ __align__(16) unsigned short comb_s[16 * LDK]; // 12544 B
    __shared__ __align__(16) float z_s[4 * 272];              // 4352 B
    __shared__ int fastok_s;
    __shared__ int role_s;

    const int tid = threadIdx.x;

    // ---- XCD-verified role claim: chain c (=role>>4) lives on XCD c>>1 ----
    if (tid == 0) {
        // HW_REG_XCC_ID = hwreg id 20 (gfx940+); getreg imm = (size-1)<<11|id
        unsigned xcc = __builtin_amdgcn_s_getreg((31u << 11) | 20u) & 7u;
        unsigned slot = atomicAdd(&boot_percxd[xcc], 1u);
        int role = -1;
        if (slot < 32u) {
            role = (int)(xcc * 32u + slot);
            atomicOr(&boot_claimed[role >> 5], 1u << (role & 31));
        }
        role_s = role;
        fastok_s = 1;
    }
    __syncthreads();
    cg::this_grid().sync();      // all claims visible before spill scan
    if (role_s < 0) {            // overflow block: grab any unclaimed role
        if (tid == 0) {
            for (int r = 0; r < 256; ++r) {
                unsigned bit = 1u << (r & 31);
                if (!(atomicOr(&boot_claimed[r >> 5], bit) & bit)) {
                    role_s = r;
                    break;
                }
            }
        }
        __syncthreads();
    }
    const int role = role_s;
    const int bg = role >> 4, jg = role & 15;   // chain bg: 16 same-XCD blocks
    const int b0 = bg * 16, j0 = jg * 16;
    const int wave = tid >> 6, lane = tid & 63;
    const int l16 = lane & 15, quad = lane >> 4;
    const int bi = tid >> 4, jj = tid & 15;
    const int b = b0 + bi, j = j0 + jj;

    // stage W tile once: local row = g*16+jr <- global row g*256+j0+jr ; 64x384
#pragma unroll
    for (int c = 0; c < 12; ++c) {
        int q = c * 256 + tid;
        int row = q / 48, c8 = q - row * 48;
        int g = row >> 4, jr = row & 15;
        short8 v = *(const short8*)(W + ((g * 256 + j0 + jr) * KDIM + c8 * 8));
        *(short8*)(&W_s[row * LDK + c8 * 8]) = v;
    }
    const float bs0 = bias[0 * HID + j];
    const float bs1 = bias[1 * HID + j];
    const float bs2 = bias[2 * HID + j];
    const float bs3 = bias[3 * HID + j];

    float c_reg = 0.f;
    float h_final = 0.f;

    const unsigned short* arow = &comb_s[l16 * LDK + quad * 8];
    const unsigned short* brow = &W_s[(wave * 16 + l16) * LDK + quad * 8];
    const int hrow = tid >> 4, hc = tid & 15;
    const int xr0 = tid >> 5, xc4 = tid & 31, xr1 = (tid + 256) >> 5;

    // prefetch x_0
    const float* xb = X + b0 * DIN;
    float4 xv0 = *(const float4*)(xb + xr0 * DIN + xc4 * 4);
    float4 xv1 = *(const float4*)(xb + xr1 * DIN + xc4 * 4);

    __syncthreads();

    for (int k = 0; k < T_STEPS; ++k) {
        const unsigned tag = (unsigned)k;
        const unsigned int* fb =
            hxp + (k & 1) * 65536 + (b0 + hrow) * HID + hc * 16;
        const unsigned int* sb = fb + 131072;    // slow plane
        uint4 a, bq, cq, d;
        const int usefast = fastok_s;            // racy read is fine (hint only)

        // ---- stage x_k from prefetched regs ----
        {
            short4v r;
            r.x = (short)f2bf(xv0.x); r.y = (short)f2bf(xv0.y);
            r.z = (short)f2bf(xv0.z); r.w = (short)f2bf(xv0.w);
            *(short4v*)(&comb_s[xr0 * LDK + xc4 * 4]) = r;
            r.x = (short)f2bf(xv1.x); r.y = (short)f2bf(xv1.y);
            r.z = (short)f2bf(xv1.z); r.w = (short)f2bf(xv1.w);
            *(short4v*)(&comb_s[xr1 * LDK + xc4 * 4]) = r;
        }

        // ---- poll h_k: fast (bounded) then slow (guaranteed) ----
        if (usefast) {
            int tries = NPOLL;
            bool ok = false;
            for (;;) {
                poll_load_sc0(fb, a, bq, cq, d);
                if (tags_ok(a, bq, cq, d, tag)) { ok = true; break; }
                if (--tries == 0) break;
            }
            if (!ok) {                       // bounded fallback: ALWAYS succeeds
                fastok_s = 0;
                for (;;) {
                    poll_load_sc1(sb, a, bq, cq, d);
                    if (tags_ok(a, bq, cq, d, tag)) break;
                    __builtin_amdgcn_s_sleep(1);
                }
            }
        } else {
            for (;;) {
                poll_load_sc1(sb, a, bq, cq, d);
                if (tags_ok(a, bq, cq, d, tag)) break;
                __builtin_amdgcn_s_sleep(1);
            }
        }

        // extract 16 bf16 -> comb_s[hrow][DIN + hc*16 ..]
        {
            uint4 p0, p1;
            p0.x = pack2bf(a.x, a.y);   p0.y = pack2bf(a.z, a.w);
            p0.z = pack2bf(bq.x, bq.y); p0.w = pack2bf(bq.z, bq.w);
            p1.x = pack2bf(cq.x, cq.y); p1.y = pack2bf(cq.z, cq.w);
            p1.z = pack2bf(d.x, d.y);   p1.w = pack2bf(d.z, d.w);
            *(uint4*)(&comb_s[hrow * LDK + DIN + hc * 16]) = p0;
            *(uint4*)(&comb_s[hrow * LDK + DIN + hc * 16 + 8]) = p1;
        }
        __syncthreads();

        // ---- MFMA: z_gate = comb[16x384] * Wg^T, 2 acc chains ----
        f32x4 acc0 = {0.f, 0.f, 0.f, 0.f}, acc1 = {0.f, 0.f, 0.f, 0.f};
#pragma unroll
        for (int kt = 0; kt < 6; ++kt) {
            short8 a0 = *(const short8*)(arow + (2 * kt) * 32);
            short8 b0v = *(const short8*)(brow + (2 * kt) * 32);
            short8 a1 = *(const short8*)(arow + (2 * kt + 1) * 32);
            short8 b1v = *(const short8*)(brow + (2 * kt + 1) * 32);
            acc0 = __builtin_amdgcn_mfma_f32_16x16x32_bf16(a0, b0v, acc0, 0, 0, 0);
            acc1 = __builtin_amdgcn_mfma_f32_16x16x32_bf16(a1, b1v, acc1, 0, 0, 0);
        }
#pragma unroll
        for (int r = 0; r < 4; ++r)
            z_s[wave * 272 + (quad * 4 + r) * 17 + l16] = acc0[r] + acc1[r];
        __syncthreads();

        // ---- gates; h dual-store FIRST (critical), then hist + x prefetch ----
        float zf = z_s[0 * 272 + bi * 17 + jj] + bs0;
        float zi = z_s[1 * 272 + bi * 17 + jj] + bs1;
        float zg = z_s[2 * 272 + bi * 17 + jj] + bs2;
        float zo = z_s[3 * 272 + bi * 17 + jj] + bs3;
        float fg = sigmoid_f(zf);
        float ig = sigmoid_f(zi);
        float gg = tanh_f(zg);
        float og = sigmoid_f(zo);
        c_reg = fg * c_reg + ig * gg;
        float hval = og * tanh_f(c_reg);
        unsigned short hb = f2bf(hval);
        unsigned int hword = ((unsigned)hb << 16) | (unsigned)(k + 1);
        unsigned int* fdst = hxp + ((k + 1) & 1) * 65536 + b * HID + j;
        store_plain_u32(fdst, hword);             // fast plane (same-XCD L2)
        store_sc1_u32(fdst + 131072, hword);      // slow plane (proven path)
        hist[(size_t)k * BATCH * HID + b * HID + j] = hb;
        if (k + 1 < T_STEPS) {
            const float* xn = X + (size_t)(k + 1) * BATCH * DIN + b0 * DIN;
            xv0 = *(const float4*)(xn + xr0 * DIN + xc4 * 4);
            xv1 = *(const float4*)(xn + xr1 * DIN + xc4 * 4);
        } else {
            h_final = hval;
        }
    }

    // epilogue: hx (fp32) and cx outputs
    out[T_STEPS * BATCH * 2 + b * HID + j] = h_final;
    out[T_STEPS * BATCH * 2 + BATCH * HID + b * HID + j] = c_reg;
}

// ---- classifier head: one wave per (t,b) row ----
__global__ __launch_bounds__(256) void probs_k(
    const unsigned short* __restrict__ hist, const float* __restrict__ Wc,
    const float* __restrict__ bc, float* __restrict__ out) {
    const int wave = threadIdx.x >> 6, lane = threadIdx.x & 63;
    const size_t row = (size_t)blockIdx.x * 4 + wave;   // row = t*256+b < 131072
    const unsigned short* h = hist + row * HID;
    short4v hv = *(const short4v*)(h + lane * 4);
    const float4 wv = *(const float4*)(Wc + lane * 4);
    float p = bf2f((unsigned short)hv.x) * wv.x + bf2f((unsigned short)hv.y) * wv.y +
              bf2f((unsigned short)hv.z) * wv.z + bf2f((unsigned short)hv.w) * wv.w;
#pragma unroll
    for (int off = 32; off >= 1; off >>= 1) p += __shfl_down(p, off);
    if (lane == 0) {
        float prob = 1.f / (1.f + __expf(-(p + bc[0])));
        out[row * 2]     = prob;
        out[row * 2 + 1] = 1.f - prob;
    }
}

extern "C" void kernel_launch(void* const* d_in, const int* in_sizes, int n_in,
                              void* d_out, int out_size, void* d_ws, size_t ws_size,
                              hipStream_t stream) {
    const float* X  = (const float*)d_in[0];
    const float* Wf = (const float*)d_in[1];
    const float* bfp= (const float*)d_in[2];
    const float* Wi = (const float*)d_in[3];
    const float* bip= (const float*)d_in[4];
    const float* Wg = (const float*)d_in[5];
    const float* bgp= (const float*)d_in[6];
    const float* Wo = (const float*)d_in[7];
    const float* bop= (const float*)d_in[8];
    const float* Wc = (const float*)d_in[9];
    const float* bc = (const float*)d_in[10];
    float* out = (float*)d_out;

    char* ws = (char*)d_ws;
    unsigned short* Wpack = (unsigned short*)(ws);               // 786432 B
    float* bias = (float*)(ws + 786432);                         // 4096 B
    unsigned int* hxp = (unsigned int*)(ws + 790528);            // 1048576 B
    unsigned short* hist = (unsigned short*)(ws + 1839104);      // 67108864 B

    pack_w<<<1536, 256, 0, stream>>>(Wf, Wi, Wg, Wo, Wpack);
    pack_b<<<4, 256, 0, stream>>>(bfp, bip, bgp, bop, bias);
    init_k<<<256, 256, 0, stream>>>(hxp);

    void* kargs[6] = {(void*)&X, (void*)&Wpack, (void*)&bias,
                      (void*)&hxp, (void*)&hist, (void*)&out};
    (void)hipLaunchCooperativeKernel((const void*)lstm_persist, dim3(GRIDN),
                                     dim3(256), kargs, 0, stream);

    probs_k<<<32768, 256, 0, stream>>>(hist, Wc, bc, out);
}